// Round 5
// baseline (155.984 us; speedup 1.0000x reference)
//
#include <hip/hip_runtime.h>

// Problem constants (from reference)
#define NUM_NODES   1200000
#define NUM_FILLER  200000
#define NUM_PHYS    (NUM_NODES - NUM_FILLER)   // 1,000,000
#define NUM_MOVABLE 900000
#define NBX 512
#define NBY 512
#define NBINS (NBX * NBY)
#define BSX 1.953125f            // 1000/512, exact in fp32
#define BSY 1.953125f
#define PIN_STRETCH 1.4142135623730951f
#define CAP 0.19073486328125f    // BSX*BSY*0.05f exactly
#define INV_CAP (1.0f / 0.19073486328125f)
#define MAX_RATE 1.5f
#define MIN_RATE (1.0f/1.5f)
#define K 5

// Spatial tiling
#define TBITS   5                // 32 bins per tile side
#define TSZ     32
#define TDIM    16               // 512/32 -> 16x16 = 256 tiles
#define NTILES  (TDIM * TDIM)
#define HALO    (K - 1)          // reference caps stencil at 5 bins -> halo 4
#define LTS     (TSZ + HALO)     // 36
#define NPB     2048             // nodes per block in the sort pass
#define NBLK    ((NUM_PHYS + NPB - 1) / NPB)   // 489
#define CAPP    6144             // phys slots/tile; E=3906, sd~62  (+36 sigma)
#define CAPM    5120             // mov  slots/tile; E=3516, sd~59  (+27 sigma)

__device__ __forceinline__ int bin_lo(float lo) {
    // matches reference: clip(floor(lo/bs), 0, nb-1); true division
    int il = (int)floorf(lo / BSX);
    return min(max(il, 0), NBX - 1);
}

// ---------------------------------------------------------------------------
// K1: fused tile sort of BOTH record streams (phys scatter boxes + movable
// gather boxes). One read of the inputs; per-block LDS histograms; one global
// cursor atomic per (block,tile,stream); LDS rank -> preallocated regions.
// ---------------------------------------------------------------------------
__global__ __launch_bounds__(256) void sort_both(
    const float* __restrict__ pos,
    const float* __restrict__ nsx,
    const float* __restrict__ nsy,
    const int*   __restrict__ flat,
    int*         __restrict__ physCur,   // [256] -> final counts
    int*         __restrict__ movCur,    // [256] -> final counts
    float4*      __restrict__ physRec,   // lox, loy, hix, hiy
    float*       __restrict__ physDens,
    float4*      __restrict__ movRec,    // xlo, ylo, xhi, yhi
    int*         __restrict__ movIdx)
{
    __shared__ int cntP[NTILES], cntM[NTILES], baseP[NTILES], baseM[NTILES];
    int tid = threadIdx.x;
    cntP[tid] = 0; cntM[tid] = 0;
    __syncthreads();

    float px[NPB/256], py[NPB/256], sx[NPB/256], sy[NPB/256], dn[NPB/256];
    int pk[NPB/256];   // bits0-7 physTile, 8-15 movTile, 16 physValid, 17 movValid
    int base = blockIdx.x * NPB;
    #pragma unroll
    for (int it = 0; it < NPB / 256; ++it) {
        int i = base + it * 256 + tid;
        int k = 0;
        if (i < NUM_PHYS) {
            float pxv = pos[i], pyv = pos[NUM_NODES + i];
            float sxv = nsx[i], syv = nsy[i];
            float hx = 0.5f * fmaxf(BSX * PIN_STRETCH, sxv);
            float hy = 0.5f * fmaxf(BSY * PIN_STRETCH, syv);
            float pw = (float)(flat[i + 1] - flat[i]);
            px[it] = pxv; py[it] = pyv; sx[it] = sxv; sy[it] = syv;
            dn[it] = pw / (4.0f * hx * hy);
            float lox = pxv + 0.5f * sxv - hx;
            float loy = pyv + 0.5f * syv - hy;
            int tp = ((bin_lo(lox) >> TBITS) << 4) | (bin_lo(loy) >> TBITS);
            atomicAdd(&cntP[tp], 1);
            k = 0x10000 | tp;
            if (i < NUM_MOVABLE) {
                int tm = ((bin_lo(pxv) >> TBITS) << 4) | (bin_lo(pyv) >> TBITS);
                atomicAdd(&cntM[tm], 1);
                k |= 0x20000 | (tm << 8);
            }
        }
        pk[it] = k;
    }
    __syncthreads();
    int cp = cntP[tid], cm = cntM[tid];
    baseP[tid] = (cp > 0) ? atomicAdd(&physCur[tid], cp) : 0;
    baseM[tid] = (cm > 0) ? atomicAdd(&movCur[tid],  cm) : 0;
    __syncthreads();
    int i0 = base + tid;
    #pragma unroll
    for (int it = 0; it < NPB / 256; ++it) {
        int k = pk[it];
        if (k & 0x10000) {
            float sxv = sx[it], syv = sy[it];
            float hx = 0.5f * fmaxf(BSX * PIN_STRETCH, sxv);
            float hy = 0.5f * fmaxf(BSY * PIN_STRETCH, syv);
            float lox = px[it] + 0.5f * sxv - hx;
            float loy = py[it] + 0.5f * syv - hy;
            int tp = k & 0xFF;
            int s = atomicAdd(&baseP[tp], 1);
            if (s < CAPP) {
                size_t g = (size_t)tp * CAPP + s;
                physRec[g] = make_float4(lox, loy, lox + 2.0f * hx, loy + 2.0f * hy);
                physDens[g] = dn[it];
            }
        }
        if (k & 0x20000) {
            int tm = (k >> 8) & 0xFF;
            int s = atomicAdd(&baseM[tm], 1);
            if (s < CAPM) {
                size_t g = (size_t)tm * CAPM + s;
                movRec[g] = make_float4(px[it], py[it],
                                        px[it] + sx[it], py[it] + sy[it]);
                movIdx[g] = i0 + it * 256;
            }
        }
    }
}

// ---------------------------------------------------------------------------
// K2: one block per tile. Tight-bounded stencil into 36x36 LDS patch with
// LDS float atomics; global atomic write-back (halo overlap between tiles).
// ---------------------------------------------------------------------------
__global__ __launch_bounds__(1024) void accumulate_tiles(
    const float4* __restrict__ physRec,
    const float*  __restrict__ physDens,
    const int*    __restrict__ physCur,
    float*        __restrict__ pin)
{
    __shared__ float tileA[LTS * LTS];
    int tid = threadIdx.x;
    int t = blockIdx.x;
    int bx0 = (t >> 4) * TSZ, by0 = (t & 15) * TSZ;

    for (int i = tid; i < LTS * LTS; i += 1024) tileA[i] = 0.0f;
    __syncthreads();

    int cnt = min(physCur[t], CAPP);
    size_t b0 = (size_t)t * CAPP;
    for (int i = tid; i < cnt; i += 1024) {
        float4 r = physRec[b0 + i];      // lox, loy, hix, hiy
        float d = physDens[b0 + i];
        int il = bin_lo(r.x), jl = bin_lo(r.y);
        int ie = min(min((int)floorf(r.z / BSX), NBX - 1), il + HALO);
        int je = min(min((int)floorf(r.w / BSY), NBY - 1), jl + HALO);
        int lr = il - bx0, lc = jl - by0;   // in [0,31]
        for (int a = il; a <= ie; ++a) {
            float blo = (float)a * BSX;
            float ox = fmaxf(fminf(r.z, blo + BSX) - fmaxf(r.x, blo), 0.0f);
            int rowb = (lr + (a - il)) * LTS + lc;
            for (int b2 = jl; b2 <= je; ++b2) {
                float blo2 = (float)b2 * BSY;
                float oy = fmaxf(fminf(r.w, blo2 + BSY) - fmaxf(r.y, blo2), 0.0f);
                float cc = ox * oy * d;
                if (cc != 0.0f) atomicAdd(&tileA[rowb + (b2 - jl)], cc);
            }
        }
    }
    __syncthreads();
    for (int i = tid; i < LTS * LTS; i += 1024) {
        float v = tileA[i];
        if (v != 0.0f) {
            int r = i / LTS, c = i % LTS;
            int gx = bx0 + r, gy = by0 + c;
            if (gx < NBX && gy < NBY) atomicAdd(&pin[gx * NBY + gy], v);
        }
    }
}

// ---------------------------------------------------------------------------
// K3: one block per tile. Stage clipped util patch (36x36) in LDS, then each
// thread gathers its tile's movable records from LDS only.
// ---------------------------------------------------------------------------
__global__ __launch_bounds__(1024) void gather_tiled(
    const float4* __restrict__ movRec,
    const int*    __restrict__ movIdx,
    const int*    __restrict__ movCur,
    const float*  __restrict__ pin,
    float*        __restrict__ out)
{
    __shared__ float patch[LTS * LTS];
    int tid = threadIdx.x;
    int t = blockIdx.x;
    int bx0 = (t >> 4) * TSZ, by0 = (t & 15) * TSZ;

    for (int i = tid; i < LTS * LTS; i += 1024) {
        int r = i / LTS, c = i % LTS;
        int gx = bx0 + r, gy = by0 + c;
        float u = MIN_RATE;
        if (gx < NBX && gy < NBY)
            u = fminf(fmaxf(pin[gx * NBY + gy] * INV_CAP, MIN_RATE), MAX_RATE);
        patch[i] = u;
    }
    __syncthreads();

    int cnt = min(movCur[t], CAPM);
    size_t b0 = (size_t)t * CAPM;
    for (int i = tid; i < cnt; i += 1024) {
        float4 r = movRec[b0 + i];       // xlo, ylo, xhi, yhi
        int idx = movIdx[b0 + i];
        int il = bin_lo(r.x), jl = bin_lo(r.y);
        int ie = min(min((int)floorf(r.z / BSX), NBX - 1), il + K - 1);
        int je = min(min((int)floorf(r.w / BSY), NBY - 1), jl + K - 1);
        int lr = il - bx0, lc = jl - by0;
        float acc = 0.0f;
        for (int a = il; a <= ie; ++a) {
            float blo = (float)a * BSX;
            float wxv = fmaxf(fminf(r.z, blo + BSX) - fmaxf(r.x, blo), 0.0f);
            int rowb = (lr + (a - il)) * LTS + lc;
            for (int b2 = jl; b2 <= je; ++b2) {
                float blo2 = (float)b2 * BSY;
                float wyv = fmaxf(fminf(r.w, blo2 + BSY) - fmaxf(r.y, blo2), 0.0f);
                acc += wxv * wyv * patch[rowb + (b2 - jl)];
            }
        }
        out[idx] = acc;
    }
}

// ---------------------------------------------------------------------------
// Fallback path (ws too small): round-1-style direct atomics + direct gather
// ---------------------------------------------------------------------------
__global__ __launch_bounds__(256) void scatter_pin_map_agent(
    const float* __restrict__ pos,
    const float* __restrict__ nsx,
    const float* __restrict__ nsy,
    const int*   __restrict__ flat,
    float*       __restrict__ map)
{
    int p = blockIdx.x * blockDim.x + threadIdx.x;
    if (p >= NUM_PHYS) return;
    float sx = nsx[p], sy = nsy[p];
    float hx = 0.5f * fmaxf(BSX * PIN_STRETCH, sx);
    float hy = 0.5f * fmaxf(BSY * PIN_STRETCH, sy);
    float cx = pos[p] + 0.5f * sx;
    float cy = pos[NUM_NODES + p] + 0.5f * sy;
    float pw = (float)(flat[p + 1] - flat[p]);
    float density = pw / (4.0f * hx * hy);
    float lox = cx - hx, hixv = cx + hx;
    float loy = cy - hy, hiyv = cy + hy;
    int il = bin_lo(lox), jl = bin_lo(loy);
    int ie = min(min((int)floorf(hixv / BSX), NBX - 1), il + K - 1);
    int je = min(min((int)floorf(hiyv / BSY), NBY - 1), jl + K - 1);
    for (int a = il; a <= ie; ++a) {
        float blo = (float)a * BSX;
        float ox = fmaxf(fminf(hixv, blo + BSX) - fmaxf(lox, blo), 0.0f);
        for (int b = jl; b <= je; ++b) {
            float blo2 = (float)b * BSY;
            float oy = fmaxf(fminf(hiyv, blo2 + BSY) - fmaxf(loy, blo2), 0.0f);
            float c = ox * oy * density;
            if (c != 0.0f) atomicAdd(&map[a * NBY + b], c);
        }
    }
}

__global__ __launch_bounds__(256) void gather_direct(
    const float* __restrict__ pos,
    const float* __restrict__ nsx,
    const float* __restrict__ nsy,
    const float* __restrict__ pin,
    float*       __restrict__ out)
{
    int m = blockIdx.x * blockDim.x + threadIdx.x;
    if (m >= NUM_MOVABLE) return;
    float xlo = pos[m];
    float xhi = xlo + nsx[m];
    float ylo = pos[NUM_NODES + m];
    float yhi = ylo + nsy[m];
    int il = bin_lo(xlo);
    int ie = min(min((int)floorf(xhi / BSX), NBX - 1), il + K - 1);
    int jl = bin_lo(ylo);
    int je = min(min((int)floorf(yhi / BSY), NBY - 1), jl + K - 1);
    float acc = 0.0f;
    for (int a = il; a <= ie; ++a) {
        float blo = (float)a * BSX;
        float wxv = fmaxf(fminf(xhi, blo + BSX) - fmaxf(xlo, blo), 0.0f);
        const float* __restrict__ row = pin + a * NBY;
        for (int b2 = jl; b2 <= je; ++b2) {
            float blo2 = (float)b2 * BSY;
            float wyv = fmaxf(fminf(yhi, blo2 + BSY) - fmaxf(ylo, blo2), 0.0f);
            float u = fminf(fmaxf(row[b2] * INV_CAP, MIN_RATE), MAX_RATE);
            acc += wxv * wyv * u;
        }
    }
    out[m] = acc;
}

extern "C" void kernel_launch(void* const* d_in, const int* in_sizes, int n_in,
                              void* d_out, int out_size, void* d_ws, size_t ws_size,
                              hipStream_t stream) {
    const float* pos  = (const float*)d_in[0];
    const float* nsx  = (const float*)d_in[1];
    const float* nsy  = (const float*)d_in[2];
    const int*   flat = (const int*)d_in[3];
    float* out = (float*)d_out;

    // Workspace layout:
    // [pin 1MB][physCur 1KB][movCur 1KB][pad to 1MB+8KB]
    // [physRec 24MB][physDens 6MB][movRec 20MB][movIdx 5MB]   total ~59 MB
    char* wsb = (char*)d_ws;
    float*  pin      = (float*)wsb;
    int*    physCur  = (int*)(wsb + (size_t)NBINS * 4);
    int*    movCur   = physCur + NTILES;
    float4* physRec  = (float4*)(wsb + (size_t)NBINS * 4 + 8192);
    float*  physDens = (float*)(physRec + (size_t)NTILES * CAPP);
    float4* movRec   = (float4*)(physDens + (size_t)NTILES * CAPP);
    int*    movIdx   = (int*)(movRec + (size_t)NTILES * CAPM);
    size_t needed = (size_t)NBINS * 4 + 8192
                  + (size_t)NTILES * CAPP * 20 + (size_t)NTILES * CAPM * 20;

    dim3 blk(256);
    if (ws_size >= needed) {
        // zero pin + both cursor arrays in one memset
        hipMemsetAsync(d_ws, 0, (size_t)NBINS * 4 + 8192, stream);
        sort_both<<<NBLK, blk, 0, stream>>>(pos, nsx, nsy, flat,
                                            physCur, movCur,
                                            physRec, physDens, movRec, movIdx);
        accumulate_tiles<<<NTILES, dim3(1024), 0, stream>>>(physRec, physDens, physCur, pin);
        gather_tiled<<<NTILES, dim3(1024), 0, stream>>>(movRec, movIdx, movCur, pin, out);
    } else {
        hipMemsetAsync(pin, 0, (size_t)NBINS * 4, stream);
        scatter_pin_map_agent<<<(NUM_PHYS + 255) / 256, blk, 0, stream>>>(pos, nsx, nsy, flat, pin);
        gather_direct<<<(NUM_MOVABLE + 255) / 256, blk, 0, stream>>>(pos, nsx, nsy, pin, out);
    }
}

// Round 6
// 146.894 us; speedup vs baseline: 1.0619x; 1.0619x over previous
//
#include <hip/hip_runtime.h>

// Problem constants (from reference)
#define NUM_NODES   1200000
#define NUM_FILLER  200000
#define NUM_PHYS    (NUM_NODES - NUM_FILLER)   // 1,000,000
#define NUM_MOVABLE 900000
#define NBX 512
#define NBY 512
#define NBINS (NBX * NBY)
#define BSX 1.953125f            // 1000/512, exact in fp32
#define BSY 1.953125f
#define PIN_STRETCH 1.4142135623730951f
#define CAP 0.19073486328125f    // BSX*BSY*0.05f exactly
#define INV_CAP (1.0f / 0.19073486328125f)
#define MAX_RATE 1.5f
#define MIN_RATE (1.0f/1.5f)
#define K 5

// Spatial tiling
#define TBITS   5                // 32 bins per tile side
#define TSZ     32
#define TDIM    16               // 512/32 -> 16x16 = 256 tiles
#define NTILES  (TDIM * TDIM)
#define HALO    (K - 1)          // stencil reaches at most il..il+4
#define LTS     (TSZ + HALO)     // 36
#define NXCD    8
#define SBLK    1024             // sort block threads
#define NPB     4096             // nodes per sort block
#define IPT     (NPB / SBLK)     // 4
#define NBLK    ((NUM_PHYS + NPB - 1) / NPB)   // 245
#define CAPX    1024             // slots per (tile,xcd); E[count]=488, sd~22

__device__ __forceinline__ int bin_lo(float lo) {
    // matches reference: clip(floor(lo/bs), 0, nb-1); true division
    int il = (int)floorf(lo / BSX);
    return min(max(il, 0), NBX - 1);
}

// ---------------------------------------------------------------------------
// K1: tile sort of phys scatter records into per-(tile,XCD) sub-regions.
// All writes to a sub-region come from one XCD -> full-line L2 writebacks
// (fixes the 2.6x write amplification measured in round 5). One global
// cursor atomic per (block,tile).
// ---------------------------------------------------------------------------
__global__ __launch_bounds__(SBLK) void sort_phys(
    const float* __restrict__ pos,
    const float* __restrict__ nsx,
    const float* __restrict__ nsy,
    const int*   __restrict__ flat,
    int*         __restrict__ cur,       // [NTILES*NXCD] -> final counts
    float4*      __restrict__ rec,       // lox, loy, hix, hiy
    float*       __restrict__ dens)
{
    __shared__ int cnt[NTILES];
    __shared__ int basep[NTILES];
    int tid = threadIdx.x;
    if (tid < NTILES) cnt[tid] = 0;
    __syncthreads();

    unsigned xcc;
    asm volatile("s_getreg_b32 %0, hwreg(HW_REG_XCC_ID, 0, 32)" : "=s"(xcc));
    xcc &= (NXCD - 1);

    float lox[IPT], loy[IPT], hix[IPT], hiy[IPT], dn[IPT];
    int tl[IPT];
    int base = blockIdx.x * NPB;
    #pragma unroll
    for (int it = 0; it < IPT; ++it) {
        int i = base + it * SBLK + tid;
        tl[it] = -1;
        if (i < NUM_PHYS) {
            float sxv = nsx[i], syv = nsy[i];
            float hx = 0.5f * fmaxf(BSX * PIN_STRETCH, sxv);
            float hy = 0.5f * fmaxf(BSY * PIN_STRETCH, syv);
            float cx = pos[i] + 0.5f * sxv;
            float cy = pos[NUM_NODES + i] + 0.5f * syv;
            float pw = (float)(flat[i + 1] - flat[i]);
            dn[it]  = pw / (4.0f * hx * hy);
            lox[it] = cx - hx; hix[it] = cx + hx;
            loy[it] = cy - hy; hiy[it] = cy + hy;
            int t = ((bin_lo(lox[it]) >> TBITS) << 4) | (bin_lo(loy[it]) >> TBITS);
            tl[it] = t;
            atomicAdd(&cnt[t], 1);
        }
    }
    __syncthreads();
    if (tid < NTILES) {
        int c = cnt[tid];
        basep[tid] = (c > 0) ? atomicAdd(&cur[tid * NXCD + xcc], c) : 0;
    }
    __syncthreads();
    #pragma unroll
    for (int it = 0; it < IPT; ++it) {
        int t = tl[it];
        if (t >= 0) {
            int s = atomicAdd(&basep[t], 1);
            if (s < CAPX) {
                size_t g = ((size_t)t * NXCD + xcc) * CAPX + s;
                rec[g] = make_float4(lox[it], loy[it], hix[it], hiy[it]);
                dens[g] = dn[it];
            }
        }
    }
}

// ---------------------------------------------------------------------------
// K2: one block per tile. Tight-bounded stencil into 36x36 LDS patch with
// LDS float atomics. Write-back: plain stores for interior bins (single
// writer), global atomics only for the 512 contested halo bins.
// ---------------------------------------------------------------------------
__global__ __launch_bounds__(1024) void accumulate_tiles(
    const float4* __restrict__ rec,
    const float*  __restrict__ dens,
    const int*    __restrict__ cur,
    float*        __restrict__ pin)
{
    __shared__ float tileA[LTS * LTS];
    int tid = threadIdx.x;
    int t = blockIdx.x;
    int bx0 = (t >> 4) * TSZ, by0 = (t & 15) * TSZ;

    for (int i = tid; i < LTS * LTS; i += 1024) tileA[i] = 0.0f;
    __syncthreads();

    for (int x = 0; x < NXCD; ++x) {
        int cnt = min(cur[t * NXCD + x], CAPX);
        size_t b0 = ((size_t)t * NXCD + x) * CAPX;
        for (int i = tid; i < cnt; i += 1024) {
            float4 r = rec[b0 + i];      // lox, loy, hix, hiy
            float d = dens[b0 + i];
            int il = bin_lo(r.x), jl = bin_lo(r.y);
            int ie = min(min((int)floorf(r.z / BSX), NBX - 1), il + HALO);
            int je = min(min((int)floorf(r.w / BSY), NBY - 1), jl + HALO);
            int lr = il - bx0, lc = jl - by0;   // in [0,31]
            for (int a = il; a <= ie; ++a) {
                float blo = (float)a * BSX;
                float ox = fmaxf(fminf(r.z, blo + BSX) - fmaxf(r.x, blo), 0.0f);
                int rowb = (lr + (a - il)) * LTS + lc;
                for (int b2 = jl; b2 <= je; ++b2) {
                    float blo2 = (float)b2 * BSY;
                    float oy = fmaxf(fminf(r.w, blo2 + BSY) - fmaxf(r.y, blo2), 0.0f);
                    float cc = ox * oy * d;
                    if (cc != 0.0f) atomicAdd(&tileA[rowb + (b2 - jl)], cc);
                }
            }
        }
    }
    __syncthreads();
    for (int i = tid; i < LTS * LTS; i += 1024) {
        float v = tileA[i];
        int r = i / LTS, c = i % LTS;
        int gx = bx0 + r, gy = by0 + c;
        if (gx >= NBX || gy >= NBY) continue;
        bool interior = (r >= HALO) && (r < TSZ) && (c >= HALO) && (c < TSZ);
        if (interior) {
            if (v != 0.0f) pin[gx * NBY + gy] = v;   // single writer, pin pre-zeroed
        } else {
            if (v != 0.0f) atomicAdd(&pin[gx * NBY + gy], v);
        }
    }
}

// ---------------------------------------------------------------------------
// K3: direct gather (coalesced out writes; pin is 1MB read-only -> L2-resident)
// ---------------------------------------------------------------------------
__global__ __launch_bounds__(256) void gather_pin_area(
    const float* __restrict__ pos,
    const float* __restrict__ nsx,
    const float* __restrict__ nsy,
    const float* __restrict__ pin,
    float*       __restrict__ out)
{
    int m = blockIdx.x * blockDim.x + threadIdx.x;
    if (m >= NUM_MOVABLE) return;

    float xlo = pos[m];
    float xhi = xlo + nsx[m];
    float ylo = pos[NUM_NODES + m];
    float yhi = ylo + nsy[m];

    int il = bin_lo(xlo);
    int ie = min(min((int)floorf(xhi / BSX), NBX - 1), il + K - 1);
    int jl = bin_lo(ylo);
    int je = min(min((int)floorf(yhi / BSY), NBY - 1), jl + K - 1);

    float acc = 0.0f;
    for (int a = il; a <= ie; ++a) {
        float blo = (float)a * BSX;
        float wxv = fmaxf(fminf(xhi, blo + BSX) - fmaxf(xlo, blo), 0.0f);
        const float* __restrict__ row = pin + a * NBY;
        for (int b2 = jl; b2 <= je; ++b2) {
            float blo2 = (float)b2 * BSY;
            float wyv = fmaxf(fminf(yhi, blo2 + BSY) - fmaxf(ylo, blo2), 0.0f);
            float u = fminf(fmaxf(row[b2] * INV_CAP, MIN_RATE), MAX_RATE);
            acc += wxv * wyv * u;
        }
    }
    out[m] = acc;
}

// ---------------------------------------------------------------------------
// Fallback path (ws too small): round-1-style direct atomics + direct gather
// ---------------------------------------------------------------------------
__global__ __launch_bounds__(256) void scatter_pin_map_agent(
    const float* __restrict__ pos,
    const float* __restrict__ nsx,
    const float* __restrict__ nsy,
    const int*   __restrict__ flat,
    float*       __restrict__ map)
{
    int p = blockIdx.x * blockDim.x + threadIdx.x;
    if (p >= NUM_PHYS) return;
    float sx = nsx[p], sy = nsy[p];
    float hx = 0.5f * fmaxf(BSX * PIN_STRETCH, sx);
    float hy = 0.5f * fmaxf(BSY * PIN_STRETCH, sy);
    float cx = pos[p] + 0.5f * sx;
    float cy = pos[NUM_NODES + p] + 0.5f * sy;
    float pw = (float)(flat[p + 1] - flat[p]);
    float density = pw / (4.0f * hx * hy);
    float lox = cx - hx, hixv = cx + hx;
    float loy = cy - hy, hiyv = cy + hy;
    int il = bin_lo(lox), jl = bin_lo(loy);
    int ie = min(min((int)floorf(hixv / BSX), NBX - 1), il + K - 1);
    int je = min(min((int)floorf(hiyv / BSY), NBY - 1), jl + K - 1);
    for (int a = il; a <= ie; ++a) {
        float blo = (float)a * BSX;
        float ox = fmaxf(fminf(hixv, blo + BSX) - fmaxf(lox, blo), 0.0f);
        for (int b = jl; b <= je; ++b) {
            float blo2 = (float)b * BSY;
            float oy = fmaxf(fminf(hiyv, blo2 + BSY) - fmaxf(loy, blo2), 0.0f);
            float c = ox * oy * density;
            if (c != 0.0f) atomicAdd(&map[a * NBY + b], c);
        }
    }
}

extern "C" void kernel_launch(void* const* d_in, const int* in_sizes, int n_in,
                              void* d_out, int out_size, void* d_ws, size_t ws_size,
                              hipStream_t stream) {
    const float* pos  = (const float*)d_in[0];
    const float* nsx  = (const float*)d_in[1];
    const float* nsy  = (const float*)d_in[2];
    const int*   flat = (const int*)d_in[3];
    float* out = (float*)d_out;

    // Workspace: [pin 1MB][cur 8KB][rec 32MB][dens 8MB]
    char* wsb = (char*)d_ws;
    float*  pin  = (float*)wsb;
    int*    cur  = (int*)(wsb + (size_t)NBINS * 4);
    float4* rec  = (float4*)(wsb + (size_t)NBINS * 4 + 8192);
    float*  dens = (float*)(rec + (size_t)NTILES * NXCD * CAPX);
    size_t needed = (size_t)NBINS * 4 + 8192
                  + (size_t)NTILES * NXCD * CAPX * 20;   // ~43 MB

    dim3 blk(256);
    if (ws_size >= needed) {
        // zero pin + cursor array in one memset
        hipMemsetAsync(d_ws, 0, (size_t)NBINS * 4 + 8192, stream);
        sort_phys<<<NBLK, dim3(SBLK), 0, stream>>>(pos, nsx, nsy, flat, cur, rec, dens);
        accumulate_tiles<<<NTILES, dim3(1024), 0, stream>>>(rec, dens, cur, pin);
    } else {
        hipMemsetAsync(pin, 0, (size_t)NBINS * 4, stream);
        scatter_pin_map_agent<<<(NUM_PHYS + 255) / 256, blk, 0, stream>>>(pos, nsx, nsy, flat, pin);
    }
    gather_pin_area<<<(NUM_MOVABLE + 255) / 256, blk, 0, stream>>>(pos, nsx, nsy, pin, out);
}